// Round 12
// baseline (178.939 us; speedup 1.0000x reference)
//
#include <hip/hip_runtime.h>
#include <stdint.h>

#define BB    2048
#define DIN   4096
#define DOUT  4096

// ---------------------------------------------------------------------------
// i8 MFMA bit-GEMM (R7/R8/R11-verified math). x,m -> ±1 int8;
// dot± = 2*sums - 4096; out = sums > thr <=> dot± > 2*thr - 4096. Exact i32.
//
// K-major panel layout (R11-verified, conflict-free):
//   x8p : [256][2048][16B] @ 0      (8 MB)   panel p = k/16, row = b
//   b8p : [256][4096][16B] @ 8 MB  (16 MB)   panel p = k/16, row = o
//
// R11 post-mortem: conflicts 4.19M -> 0 but time flat (51.5us) -> stalls
// mask the LDS pipe. Calibration from R7->R8: each __syncthreads exposes
// ~950cyc of vmcnt(0) drain on prefetch loads issued only ~400cyc earlier.
// R12: restructured K-loop — BK=64, triple-buffer LDS (48 KB, keeps
// 2 blocks/CU per R9 lesson), prefetch depth 2, and raw
// `s_waitcnt vmcnt(4); s_barrier` (inline asm, never vmcnt(0)): wait only
// the OLDER chunk's 4 loads (issued ~2 chunk-periods ago), newest stay in
// flight. Buffer (c+2)%3 reuse is protected by the barrier ending chunk c-1.
// Spill canary: WRITE_SIZE > 32.8 MB.
// ---------------------------------------------------------------------------

using v4i  = __attribute__((ext_vector_type(4)))  int;
using v16i = __attribute__((ext_vector_type(16))) int;

__device__ __forceinline__ void async_load16(const void* g, void* l) {
    __builtin_amdgcn_global_load_lds(
        (const __attribute__((address_space(1))) unsigned int*)g,
        (__attribute__((address_space(3))) unsigned int*)l,
        16, 0, 0);
}

// wait until <=4 of this wave's vmem ops outstanding, then workgroup barrier.
// NOT __syncthreads(): that drains vmcnt(0) and re-exposes the ~950cyc stall.
__device__ __forceinline__ void barrier_vm4() {
    asm volatile("s_waitcnt vmcnt(4)\n\ts_barrier" ::: "memory");
}

// bytes {0,1} -> {+1, -1(0xFF)}; no cross-byte carries.
__device__ __forceinline__ unsigned int to_pm1(unsigned int c) {
    return c + ((c ^ 0x01010101u) * 255u);
}

// Fused packing (R11-verified).
// blocks [0,256): x -> x8p K-major; 16-B stores wave-coalesced (1 KB).
// blocks [256, 256+4096): 64x64 mask transpose tile (v_perm) -> b8p K-major.
__global__ void pack_all(const int* __restrict__ x,
                         const void* __restrict__ mraw,
                         char* __restrict__ x8p,
                         char* __restrict__ b8p) {
    const int tid = threadIdx.x;
    if (blockIdx.x < 256) {
        const int br  = blockIdx.x & 31;          // row tile (64 rows)
        const int bp  = blockIdx.x >> 5;          // panel tile (32 panels)
        const int row = br * 64 + (tid & 63);
        const int w   = tid >> 6;
        #pragma unroll
        for (int j = 0; j < 8; ++j) {
            const int p = bp * 32 + w * 8 + j;    // global panel, k=[16p,16p+16)
            const int4* src = (const int4*)(x + (size_t)row * DIN + p * 16);
            int4 a0 = src[0], a1 = src[1], a2 = src[2], a3 = src[3];
            uint4 v;
            v.x = to_pm1((unsigned)(a0.x & 1) | ((unsigned)(a0.y & 1) << 8) |
                         ((unsigned)(a0.z & 1) << 16) | ((unsigned)(a0.w & 1) << 24));
            v.y = to_pm1((unsigned)(a1.x & 1) | ((unsigned)(a1.y & 1) << 8) |
                         ((unsigned)(a1.z & 1) << 16) | ((unsigned)(a1.w & 1) << 24));
            v.z = to_pm1((unsigned)(a2.x & 1) | ((unsigned)(a2.y & 1) << 8) |
                         ((unsigned)(a2.z & 1) << 16) | ((unsigned)(a2.w & 1) << 24));
            v.w = to_pm1((unsigned)(a3.x & 1) | ((unsigned)(a3.y & 1) << 8) |
                         ((unsigned)(a3.z & 1) << 16) | ((unsigned)(a3.w & 1) << 24));
            *(uint4*)(x8p + ((size_t)p * 2048 + row) * 16) = v;   // coalesced
        }
    } else {
        const int bw = blockIdx.x - 256;           // 0..4095
        const int k0 = (bw & 63) * 64;
        const int n0 = (bw >> 6) * 64;

        // inline dtype detect (u8-bool vs int32): wave-reduce 1 KB prefix.
        const unsigned char* mb = (const unsigned char*)mraw;
        int myv = (mb[tid] != 0) + (mb[tid + 256] != 0) +
                  (mb[tid + 512] != 0) + (mb[tid + 768] != 0);
        #pragma unroll
        for (int d = 32; d; d >>= 1) myv += __shfl_xor(myv, d);
        const bool isU8 = (myv > 64);   // u8 ~128/wave, int32 ~32/wave

        // 4x4 byte micro-tile: rows k0+k4..+3, cols n0+n4..+3
        const int n4 = (tid & 15) * 4;
        const int k4 = (tid >> 4) * 4;
        unsigned int a[4];
        if (isU8) {
            #pragma unroll
            for (int r = 0; r < 4; ++r)
                a[r] = *(const unsigned int*)(mb + (size_t)(k0 + k4 + r) * DOUT + n0 + n4);
        } else {
            const int4* m32 = (const int4*)mraw;
            #pragma unroll
            for (int r = 0; r < 4; ++r) {
                int4 v = m32[((size_t)(k0 + k4 + r) * DOUT + n0 + n4) >> 2];
                a[r] = (unsigned int)(v.x & 1) |
                       ((unsigned int)(v.y & 1) << 8) |
                       ((unsigned int)(v.z & 1) << 16) |
                       ((unsigned int)(v.w & 1) << 24);
            }
        }
        // 4x4 byte transpose via v_perm (verified R7)
        unsigned int x0 = __builtin_amdgcn_perm(a[1], a[0], 0x05010400u);
        unsigned int x1 = __builtin_amdgcn_perm(a[3], a[2], 0x05010400u);
        unsigned int x2 = __builtin_amdgcn_perm(a[1], a[0], 0x07030602u);
        unsigned int x3 = __builtin_amdgcn_perm(a[3], a[2], 0x07030602u);
        unsigned int c0 = __builtin_amdgcn_perm(x1, x0, 0x05040100u);
        unsigned int c1 = __builtin_amdgcn_perm(x1, x0, 0x07060302u);
        unsigned int c2 = __builtin_amdgcn_perm(x3, x2, 0x05040100u);
        unsigned int c3 = __builtin_amdgcn_perm(x3, x2, 0x07060302u);
        const int p   = (k0 + k4) >> 4;            // global panel
        const int off = k4 & 15;                   // byte offset in 16-B group
        *(unsigned int*)(b8p + ((size_t)p * 4096 + n0 + n4 + 0) * 16 + off) = to_pm1(c0);
        *(unsigned int*)(b8p + ((size_t)p * 4096 + n0 + n4 + 1) * 16 + off) = to_pm1(c1);
        *(unsigned int*)(b8p + ((size_t)p * 4096 + n0 + n4 + 2) * 16 + off) = to_pm1(c2);
        *(unsigned int*)(b8p + ((size_t)p * 4096 + n0 + n4 + 3) * 16 + off) = to_pm1(c3);
    }
}

// i8 MFMA GEMM: 128x128 block tile, 4 waves 2x2 (T=U=2 of 32x32x32_i8).
// BK=64 = 4 K-panels/chunk, 64 chunks, TRIPLE-buffered LDS (48 KB,
// 2 blocks/CU), prefetch depth 2, vmcnt(4) barriers (never full drain).
__global__ __launch_bounds__(256)
void bgemm(const char* __restrict__ x8p,
           const char* __restrict__ b8p,
           const int* __restrict__ thr,
           int* __restrict__ out) {
    // XCD swizzle (verified R8): flat%8 = XCD, 8x8-block patch per XCD.
    const int flat = blockIdx.y * 32 + blockIdx.x;
    const int xcd  = flat & 7;
    const int idx  = flat >> 3;                    // 0..63
    const int bm   = (xcd & 1) * 8 + (idx & 7);    // 0..15
    const int bn   = (xcd >> 1) * 8 + (idx >> 3);  // 0..31
    const int m0   = bm * 128;
    const int o0   = bn * 128;

    const int tid  = threadIdx.x;
    const int lane = tid & 63;
    const int wv   = tid >> 6;           // wave 0..3
    const int wm   = (wv & 1) * 64;      // wave tile m origin
    const int wn   = (wv >> 1) * 64;     // wave tile n origin
    const int l31  = lane & 31;
    const int lh   = lane >> 5;

    __shared__ __align__(16) char lA[3][4 * 128 * 16];   // 3 x 8 KB
    __shared__ __align__(16) char lB[3][4 * 128 * 16];   // 3 x 8 KB

    // stage chunk c (panels 4c..4c+3): wave wv stages panel wv of A and B,
    // 2 contiguous 1-KB instrs each -> 4 vmem ops per wave per chunk.
    auto stage = [&](int c, int buf) {
        const int pg = 4 * c + wv;                 // global panel
        #pragma unroll
        for (int h = 0; h < 2; ++h) {
            const int r = h * 64 + lane;
            async_load16(x8p + ((size_t)pg * 2048 + m0 + r) * 16,
                         &lA[buf][(wv * 128 + r) * 16]);
            async_load16(b8p + ((size_t)pg * 4096 + o0 + r) * 16,
                         &lB[buf][(wv * 128 + r) * 16]);
        }
    };

    v16i acc[2][2];
    #pragma unroll
    for (int t = 0; t < 2; ++t)
        #pragma unroll
        for (int u = 0; u < 2; ++u)
            acc[t][u] = (v16i)(0);

    stage(0, 0);
    stage(1, 1);
    barrier_vm4();          // oldest 4 (chunk 0) done; chunk 1 may fly

    int bufc = 0;           // buffer holding chunk c
    for (int c = 0; c < 64; ++c) {
        const int bufp2 = (bufc >= 1) ? bufc - 1 : bufc + 2;   // (c+2)%3
        if (c < 62) stage(c + 2, bufp2);

        #pragma unroll
        for (int ks = 0; ks < 2; ++ks) {
            // MFMA ks consumes local panels 2ks (lanes 0-31) / 2ks+1 (32-63)
            const int poff = (2 * ks + lh) * 2048;
            v4i aF[2], bF[2];
            #pragma unroll
            for (int t = 0; t < 2; ++t) {
                aF[t] = *(const v4i*)&lA[bufc][poff + (wm + t * 32 + l31) * 16];
                bF[t] = *(const v4i*)&lB[bufc][poff + (wn + t * 32 + l31) * 16];
            }
            acc[0][0] = __builtin_amdgcn_mfma_i32_32x32x32_i8(aF[0], bF[0], acc[0][0], 0, 0, 0);
            acc[0][1] = __builtin_amdgcn_mfma_i32_32x32x32_i8(aF[0], bF[1], acc[0][1], 0, 0, 0);
            acc[1][0] = __builtin_amdgcn_mfma_i32_32x32x32_i8(aF[1], bF[0], acc[1][0], 0, 0, 0);
            acc[1][1] = __builtin_amdgcn_mfma_i32_32x32x32_i8(aF[1], bF[1], acc[1][1], 0, 0, 0);
        }

        // ensure chunk c+1's loads (issued last iteration) are done; only
        // chunk c+2's 4 loads may remain in flight. All waves past reads of
        // bufc -> safe to overwrite it (it becomes (c+3)%3 next+1 iter).
        barrier_vm4();
        bufc = (bufc >= 2) ? 0 : bufc + 1;
    }

    // epilogue: out = (dot± > 2*thr - 4096).
    // C/D layout (verified R7/R8): col = lane&31; row = (reg&3)+8*(reg>>2)+4*(lane>>5).
    #pragma unroll
    for (int u = 0; u < 2; ++u) {
        const int o   = o0 + wn + u * 32 + l31;
        const int lim = 2 * thr[o] - DIN;
        #pragma unroll
        for (int t = 0; t < 2; ++t) {
            #pragma unroll
            for (int r = 0; r < 16; ++r) {
                const int rowl = (r & 3) + 8 * (r >> 2) + 4 * lh;
                const int b    = m0 + wm + t * 32 + rowl;
                out[(size_t)b * DOUT + o] = (acc[t][u][r] > lim) ? 1 : 0;
            }
        }
    }
}

extern "C" void kernel_launch(void* const* d_in, const int* in_sizes, int n_in,
                              void* d_out, int out_size, void* d_ws, size_t ws_size,
                              hipStream_t stream) {
    const int* x          = (const int*)d_in[0];
    const void* masks     = d_in[1];           // bool: u8 or int32 (detected inline)
    const int* thresholds = (const int*)d_in[2];
    int* out              = (int*)d_out;

    char* x8p = (char*)d_ws;                          // 8 MB
    char* b8p = (char*)d_ws + ((size_t)8 << 20);      // 16 MB

    pack_all<<<256 + 4096, 256, 0, stream>>>(x, masks, x8p, b8p);
    bgemm<<<dim3(32, 16), 256, 0, stream>>>(x8p, b8p, thresholds, out);
}

// Round 13
// 177.847 us; speedup vs baseline: 1.0061x; 1.0061x over previous
//
#include <hip/hip_runtime.h>
#include <stdint.h>

#define BB    2048
#define DIN   4096
#define DOUT  4096

// ---------------------------------------------------------------------------
// i8 MFMA bit-GEMM (R7/R8/R11-verified math). x,m -> ±1 int8;
// dot± = 2*sums - 4096; out = sums > thr <=> dot± > 2*thr - 4096. Exact i32.
//
// K-major panel layout (R11-verified):
//   x8p : [256][2048][16B] @ 0      (8 MB)   panel p = k/16, row = b
//   b8p : [256][4096][16B] @ 8 MB  (16 MB)   panel p = k/16, row = o
//
// R8/R11/R12 = 48/51.5/53.8us: every LDS-staged K-loop shape plateaus ~50us.
// MfmaUtil pinned 25%; compiler force-drains vmcnt(0) before ds_reads of
// global_load_lds data (m131-class defeat), and barrier lockstep phases the
// LDS pipe (27us busy) against MFMA (13.6us) instead of overlapping.
//
// R13: NO LDS AT ALL. In K-major layout a wave's MFMA fragment IS a
// contiguous global segment (2 x 512B per instr) -> global_load_dwordx4
// straight to VGPR, register pipeline depth 4, zero barriers, free-running
// waves (AITER-style fine-grained vmcnt emerges naturally on plain loads).
// Traffic: 2x reuse amplification = 4 MB/CU from L2 (~13us) vs LDS-pipe 27.
// launch_bounds(256,2): VGPR cap 256 (acc 64 + frags 64 + addr; R4 lesson).
// Spill canary: WRITE_SIZE > 32.8 MB.
// ---------------------------------------------------------------------------

using v4i  = __attribute__((ext_vector_type(4)))  int;
using v16i = __attribute__((ext_vector_type(16))) int;

// bytes {0,1} -> {+1, -1(0xFF)}; no cross-byte carries.
__device__ __forceinline__ unsigned int to_pm1(unsigned int c) {
    return c + ((c ^ 0x01010101u) * 255u);
}

// Fused packing (R11-verified, unchanged).
// blocks [0,256): x -> x8p K-major; 16-B stores wave-coalesced (1 KB).
// blocks [256, 256+4096): 64x64 mask transpose tile (v_perm) -> b8p K-major.
__global__ void pack_all(const int* __restrict__ x,
                         const void* __restrict__ mraw,
                         char* __restrict__ x8p,
                         char* __restrict__ b8p) {
    const int tid = threadIdx.x;
    if (blockIdx.x < 256) {
        const int br  = blockIdx.x & 31;          // row tile (64 rows)
        const int bp  = blockIdx.x >> 5;          // panel tile (32 panels)
        const int row = br * 64 + (tid & 63);
        const int w   = tid >> 6;
        #pragma unroll
        for (int j = 0; j < 8; ++j) {
            const int p = bp * 32 + w * 8 + j;    // global panel, k=[16p,16p+16)
            const int4* src = (const int4*)(x + (size_t)row * DIN + p * 16);
            int4 a0 = src[0], a1 = src[1], a2 = src[2], a3 = src[3];
            uint4 v;
            v.x = to_pm1((unsigned)(a0.x & 1) | ((unsigned)(a0.y & 1) << 8) |
                         ((unsigned)(a0.z & 1) << 16) | ((unsigned)(a0.w & 1) << 24));
            v.y = to_pm1((unsigned)(a1.x & 1) | ((unsigned)(a1.y & 1) << 8) |
                         ((unsigned)(a1.z & 1) << 16) | ((unsigned)(a1.w & 1) << 24));
            v.z = to_pm1((unsigned)(a2.x & 1) | ((unsigned)(a2.y & 1) << 8) |
                         ((unsigned)(a2.z & 1) << 16) | ((unsigned)(a2.w & 1) << 24));
            v.w = to_pm1((unsigned)(a3.x & 1) | ((unsigned)(a3.y & 1) << 8) |
                         ((unsigned)(a3.z & 1) << 16) | ((unsigned)(a3.w & 1) << 24));
            *(uint4*)(x8p + ((size_t)p * 2048 + row) * 16) = v;   // coalesced
        }
    } else {
        const int bw = blockIdx.x - 256;           // 0..4095
        const int k0 = (bw & 63) * 64;
        const int n0 = (bw >> 6) * 64;

        // inline dtype detect (u8-bool vs int32): wave-reduce 1 KB prefix.
        const unsigned char* mb = (const unsigned char*)mraw;
        int myv = (mb[tid] != 0) + (mb[tid + 256] != 0) +
                  (mb[tid + 512] != 0) + (mb[tid + 768] != 0);
        #pragma unroll
        for (int d = 32; d; d >>= 1) myv += __shfl_xor(myv, d);
        const bool isU8 = (myv > 64);   // u8 ~128/wave, int32 ~32/wave

        // 4x4 byte micro-tile: rows k0+k4..+3, cols n0+n4..+3
        const int n4 = (tid & 15) * 4;
        const int k4 = (tid >> 4) * 4;
        unsigned int a[4];
        if (isU8) {
            #pragma unroll
            for (int r = 0; r < 4; ++r)
                a[r] = *(const unsigned int*)(mb + (size_t)(k0 + k4 + r) * DOUT + n0 + n4);
        } else {
            const int4* m32 = (const int4*)mraw;
            #pragma unroll
            for (int r = 0; r < 4; ++r) {
                int4 v = m32[((size_t)(k0 + k4 + r) * DOUT + n0 + n4) >> 2];
                a[r] = (unsigned int)(v.x & 1) |
                       ((unsigned int)(v.y & 1) << 8) |
                       ((unsigned int)(v.z & 1) << 16) |
                       ((unsigned int)(v.w & 1) << 24);
            }
        }
        // 4x4 byte transpose via v_perm (verified R7)
        unsigned int x0 = __builtin_amdgcn_perm(a[1], a[0], 0x05010400u);
        unsigned int x1 = __builtin_amdgcn_perm(a[3], a[2], 0x05010400u);
        unsigned int x2 = __builtin_amdgcn_perm(a[1], a[0], 0x07030602u);
        unsigned int x3 = __builtin_amdgcn_perm(a[3], a[2], 0x07030602u);
        unsigned int c0 = __builtin_amdgcn_perm(x1, x0, 0x05040100u);
        unsigned int c1 = __builtin_amdgcn_perm(x1, x0, 0x07060302u);
        unsigned int c2 = __builtin_amdgcn_perm(x3, x2, 0x05040100u);
        unsigned int c3 = __builtin_amdgcn_perm(x3, x2, 0x07060302u);
        const int p   = (k0 + k4) >> 4;            // global panel
        const int off = k4 & 15;                   // byte offset in 16-B group
        *(unsigned int*)(b8p + ((size_t)p * 4096 + n0 + n4 + 0) * 16 + off) = to_pm1(c0);
        *(unsigned int*)(b8p + ((size_t)p * 4096 + n0 + n4 + 1) * 16 + off) = to_pm1(c1);
        *(unsigned int*)(b8p + ((size_t)p * 4096 + n0 + n4 + 2) * 16 + off) = to_pm1(c2);
        *(unsigned int*)(b8p + ((size_t)p * 4096 + n0 + n4 + 3) * 16 + off) = to_pm1(c3);
    }
}

// i8 MFMA GEMM, LDS-FREE: 128x128 block tile, 4 waves 2x2 (T=U=2 of
// 32x32x32_i8). 128 K-steps; fragments loaded global->VGPR (each load =
// 2 contiguous 512B segments, L2-resident), register pipeline depth 4,
// no barriers. Frag address for step ks, half-wave lh: panel 2*ks+lh.
__global__ __launch_bounds__(256, 2)
void bgemm(const char* __restrict__ x8p,
           const char* __restrict__ b8p,
           const int* __restrict__ thr,
           int* __restrict__ out) {
    // XCD swizzle (verified R8): flat%8 = XCD, 8x8-block patch per XCD.
    const int flat = blockIdx.y * 32 + blockIdx.x;
    const int xcd  = flat & 7;
    const int idx  = flat >> 3;                    // 0..63
    const int bm   = (xcd & 1) * 8 + (idx & 7);    // 0..15
    const int bn   = (xcd >> 1) * 8 + (idx >> 3);  // 0..31
    const int m0   = bm * 128;
    const int o0   = bn * 128;

    const int tid  = threadIdx.x;
    const int lane = tid & 63;
    const int wv   = tid >> 6;           // wave 0..3
    const int wm   = (wv & 1) * 64;      // wave tile m origin
    const int wn   = (wv >> 1) * 64;     // wave tile n origin
    const int l31  = lane & 31;
    const int lh   = lane >> 5;

    // per-lane fragment base pointers (advance by 2 panels per K-step)
    const char* pA[2];
    const char* pB[2];
    #pragma unroll
    for (int t = 0; t < 2; ++t)
        pA[t] = x8p + ((size_t)lh * 2048 + m0 + wm + t * 32 + l31) * 16;
    #pragma unroll
    for (int u = 0; u < 2; ++u)
        pB[u] = b8p + ((size_t)lh * 4096 + o0 + wn + u * 32 + l31) * 16;

    v16i acc[2][2];
    #pragma unroll
    for (int t = 0; t < 2; ++t)
        #pragma unroll
        for (int u = 0; u < 2; ++u)
            acc[t][u] = (v16i)(0);

    // register pipeline, depth 4
    v4i aF[4][2], bF[4][2];
    auto loadf = [&](int ks, int buf) {
        #pragma unroll
        for (int t = 0; t < 2; ++t)
            aF[buf][t] = *(const v4i*)(pA[t] + (size_t)ks * 65536);    // 2*2048*16
        #pragma unroll
        for (int u = 0; u < 2; ++u)
            bF[buf][u] = *(const v4i*)(pB[u] + (size_t)ks * 131072);   // 2*4096*16
    };
    auto mfmas = [&](int buf) {
        acc[0][0] = __builtin_amdgcn_mfma_i32_32x32x32_i8(aF[buf][0], bF[buf][0], acc[0][0], 0, 0, 0);
        acc[0][1] = __builtin_amdgcn_mfma_i32_32x32x32_i8(aF[buf][0], bF[buf][1], acc[0][1], 0, 0, 0);
        acc[1][0] = __builtin_amdgcn_mfma_i32_32x32x32_i8(aF[buf][1], bF[buf][0], acc[1][0], 0, 0, 0);
        acc[1][1] = __builtin_amdgcn_mfma_i32_32x32x32_i8(aF[buf][1], bF[buf][1], acc[1][1], 0, 0, 0);
    };

    #pragma unroll
    for (int ks = 0; ks < 4; ++ks) loadf(ks, ks);
    #pragma unroll 4
    for (int ks = 0; ks < 124; ++ks) {
        const int buf = ks & 3;
        mfmas(buf);
        loadf(ks + 4, buf);      // refill consumed buffer, 4 steps ahead
    }
    #pragma unroll
    for (int ks = 124; ks < 128; ++ks) mfmas(ks & 3);

    // epilogue: out = (dot± > 2*thr - 4096).
    // C/D layout (verified R7/R8): col = lane&31; row = (reg&3)+8*(reg>>2)+4*(lane>>5).
    #pragma unroll
    for (int u = 0; u < 2; ++u) {
        const int o   = o0 + wn + u * 32 + l31;
        const int lim = 2 * thr[o] - DIN;
        #pragma unroll
        for (int t = 0; t < 2; ++t) {
            #pragma unroll
            for (int r = 0; r < 16; ++r) {
                const int rowl = (r & 3) + 8 * (r >> 2) + 4 * lh;
                const int b    = m0 + wm + t * 32 + rowl;
                out[(size_t)b * DOUT + o] = (acc[t][u][r] > lim) ? 1 : 0;
            }
        }
    }
}

extern "C" void kernel_launch(void* const* d_in, const int* in_sizes, int n_in,
                              void* d_out, int out_size, void* d_ws, size_t ws_size,
                              hipStream_t stream) {
    const int* x          = (const int*)d_in[0];
    const void* masks     = d_in[1];           // bool: u8 or int32 (detected inline)
    const int* thresholds = (const int*)d_in[2];
    int* out              = (int*)d_out;

    char* x8p = (char*)d_ws;                          // 8 MB
    char* b8p = (char*)d_ws + ((size_t)8 << 20);      // 16 MB

    pack_all<<<256 + 4096, 256, 0, stream>>>(x, masks, x8p, b8p);
    bgemm<<<dim3(32, 16), 256, 0, stream>>>(x8p, b8p, thresholds, out);
}